// Round 3
// baseline (19067.157 us; speedup 1.0000x reference)
//
#include <hip/hip_runtime.h>

// SNN B=128, D0=512, T=512, dims 1024/1024/512, DECAY=0.5, THRESH=0.3
// Round 3: factor the whole network into 3 big parallel GEMMs + 3 elementwise
// temporal scans (per-neuron recurrence carried in registers). 10 launches total.

typedef __bf16 bf16;
typedef __attribute__((ext_vector_type(8))) __bf16 bf16x8;
typedef __attribute__((ext_vector_type(4))) float f32x4;

#define B_   128
#define D0_  512
#define T_   512
#define N1_  1024
#define N2_  1024
#define N3_  512
#define TB_  (T_ * B_)
#define MFMA16(a,b,c) __builtin_amdgcn_mfma_f32_16x16x32_bf16((a),(b),(c),0,0,0)

// ---------- setup ----------

// inputs [B][D0][T] fp32 -> Xh/Xl [T*B][D0] bf16 (hi/lo split, time-major)
__global__ __launch_bounds__(256)
void split_x(const float* __restrict__ in, bf16* __restrict__ Xh, bf16* __restrict__ Xl)
{
    __shared__ float tile[32][33];
    const int b = blockIdx.z, d0 = blockIdx.x * 32, t0 = blockIdx.y * 32;
    const int tx = threadIdx.x & 31, ty = threadIdx.x >> 5;
#pragma unroll
    for (int r = 0; r < 4; ++r) {
        int d = ty + r * 8;
        tile[d][tx] = in[((size_t)b * D0_ + d0 + d) * T_ + t0 + tx];
    }
    __syncthreads();
#pragma unroll
    for (int r = 0; r < 4; ++r) {
        int t = ty + r * 8;
        float v = tile[tx][t];
        bf16 h = (bf16)v;
        size_t o = ((size_t)(t0 + t) * B_ + b) * D0_ + d0 + tx;
        Xh[o] = h;
        Xl[o] = (bf16)(v - (float)h);
    }
}

// W [K][N] fp32 -> WTh/WTl [N][K] bf16 (transposed hi/lo split)
__global__ __launch_bounds__(256)
void split_w(const float* __restrict__ W, bf16* __restrict__ WTh, bf16* __restrict__ WTl,
             int K, int N)
{
    __shared__ float tile[32][33];
    const int k0 = blockIdx.x * 32, n0 = blockIdx.y * 32;
    const int tx = threadIdx.x & 31, ty = threadIdx.x >> 5;
#pragma unroll
    for (int r = 0; r < 4; ++r)
        tile[ty + r * 8][tx] = W[(size_t)(k0 + ty + r * 8) * N + n0 + tx];
    __syncthreads();
#pragma unroll
    for (int r = 0; r < 4; ++r) {
        int nl = ty + r * 8;
        float v = tile[tx][nl];
        bf16 h = (bf16)v;
        size_t o = (size_t)(n0 + nl) * K + k0 + tx;
        WTh[o] = h;
        WTl[o] = (bf16)(v - (float)h);
    }
}

// ---------- big GEMM: C[M][N] = A[M][K] @ WT[N][K]^T ----------
// block 256 thr = 4 waves; block tile 128x128, wave quadrant 64x64 (4x4 frags).
// SPLITA: A has hi/lo parts (3-term split); else A is exact bf16 (spikes), 2-term.
template<int K, bool SPLITA>
__global__ __launch_bounds__(256)
void gemm128(const bf16* __restrict__ Ah, const bf16* __restrict__ Al,
             const bf16* __restrict__ WTh, const bf16* __restrict__ WTl,
             float* __restrict__ C, int N)
{
    const int tid = threadIdx.x, lane = tid & 63, w = tid >> 6;
    const int wm = w & 1, wn = w >> 1;
    const int r15 = lane & 15, q = lane >> 4, kq = q * 8;
    const size_t mb = (size_t)blockIdx.y * 128 + wm * 64;
    const int nb = blockIdx.x * 128 + wn * 64;

    const bf16* aph[4]; const bf16* apl[4];
    const bf16* bph[4]; const bf16* bpl[4];
#pragma unroll
    for (int i = 0; i < 4; ++i) {
        aph[i] = Ah + (mb + i * 16 + r15) * K + kq;
        if (SPLITA) apl[i] = Al + (mb + i * 16 + r15) * K + kq;
        bph[i] = WTh + (size_t)(nb + i * 16 + r15) * K + kq;
        bpl[i] = WTl + (size_t)(nb + i * 16 + r15) * K + kq;
    }

    f32x4 acc[4][4] = {};
#pragma unroll 4
    for (int s = 0; s < K / 32; ++s) {
        bf16x8 a[4], al[4], bh[4], bl[4];
#pragma unroll
        for (int i = 0; i < 4; ++i) {
            a[i]  = *(const bf16x8*)(aph[i] + s * 32);
            if (SPLITA) al[i] = *(const bf16x8*)(apl[i] + s * 32);
            bh[i] = *(const bf16x8*)(bph[i] + s * 32);
            bl[i] = *(const bf16x8*)(bpl[i] + s * 32);
        }
#pragma unroll
        for (int mi = 0; mi < 4; ++mi)
#pragma unroll
            for (int ni = 0; ni < 4; ++ni) {
                acc[mi][ni] = MFMA16(a[mi], bh[ni], acc[mi][ni]);
                if (SPLITA) {
                    acc[mi][ni] = MFMA16(al[mi], bh[ni], acc[mi][ni]);
                    acc[mi][ni] = MFMA16(a[mi],  bl[ni], acc[mi][ni]);
                } else {
                    acc[mi][ni] = MFMA16(a[mi],  bl[ni], acc[mi][ni]);
                }
            }
    }
#pragma unroll
    for (int mi = 0; mi < 4; ++mi)
#pragma unroll
        for (int ni = 0; ni < 4; ++ni)
#pragma unroll
            for (int r = 0; r < 4; ++r)
                C[(mb + mi * 16 + q * 4 + r) * N + nb + ni * 16 + r15] = acc[mi][ni][r];
}

// ---------- temporal scans (parallel over neurons, sequential over t) ----------

// I [T][BN] f32 -> S [T][BN] bf16 spike train
__global__ __launch_bounds__(256)
void scan_train(const float* __restrict__ I, bf16* __restrict__ S, int BN)
{
    const int i = blockIdx.x * 256 + threadIdx.x;
    float m = 0.f, s = 0.f;
#pragma unroll 8
    for (int t = 0; t < T_; ++t) {
        float v = I[(size_t)t * BN + i];
        m = m * 0.5f * (1.0f - s) + v;
        s = (m > 0.3f) ? 1.0f : 0.0f;
        S[(size_t)t * BN + i] = (bf16)s;
    }
}

// I [T][BN] f32 -> out [BN] f32 (final-step spikes only)
__global__ __launch_bounds__(256)
void scan_out(const float* __restrict__ I, float* __restrict__ out, int BN)
{
    const int i = blockIdx.x * 256 + threadIdx.x;
    float m = 0.f, s = 0.f;
#pragma unroll 8
    for (int t = 0; t < T_; ++t) {
        float v = I[(size_t)t * BN + i];
        m = m * 0.5f * (1.0f - s) + v;
        s = (m > 0.3f) ? 1.0f : 0.0f;
    }
    out[i] = s;
}

// ---------- fallback per-step kernels (round-2, used if ws too small) ----------

__global__ __launch_bounds__(256)
void stage_mid(const bf16* __restrict__ Ab, const bf16* __restrict__ WTh,
               const bf16* __restrict__ WTl, float* __restrict__ mem, bf16* __restrict__ spkb)
{
    const int tid = threadIdx.x, lane = tid & 63, w = tid >> 6;
    const int mh = w & 1, kh = w >> 1;
    const int m0 = blockIdx.y * 32 + mh * 16;
    const int q = lane >> 4, kq = q * 8;
    const bf16* ap  = Ab  + (size_t)(m0 + (lane & 15)) * N1_ + kh * 512 + kq;
    const bf16* bhp = WTh + (size_t)(blockIdx.x * 16 + (lane & 15)) * N1_ + kh * 512 + kq;
    const bf16* blp = WTl + (size_t)(blockIdx.x * 16 + (lane & 15)) * N1_ + kh * 512 + kq;
    f32x4 acc = {0, 0, 0, 0};
#pragma unroll 8
    for (int s = 0; s < 16; ++s) {
        bf16x8 a = *(const bf16x8*)(ap + s * 32);
        acc = MFMA16(a, *(const bf16x8*)(bhp + s * 32), acc);
        acc = MFMA16(a, *(const bf16x8*)(blp + s * 32), acc);
    }
    __shared__ f32x4 red[2][64];
    if (kh == 1) red[mh][lane] = acc;
    __syncthreads();
    if (kh == 0) {
        f32x4 o = red[mh][lane];
        acc.x += o.x; acc.y += o.y; acc.z += o.z; acc.w += o.w;
#pragma unroll
        for (int r = 0; r < 4; ++r) {
            size_t idx = (size_t)(m0 + q * 4 + r) * N2_ + blockIdx.x * 16 + (lane & 15);
            float m = mem[idx] * 0.5f * (1.0f - (float)spkb[idx]) + acc[r];
            mem[idx] = m;
            spkb[idx] = (m > 0.3f) ? (bf16)1.0f : (bf16)0.0f;
        }
    }
}

__global__ __launch_bounds__(256)
void stage_last(const bf16* __restrict__ Ab, const bf16* __restrict__ WTh,
                const bf16* __restrict__ WTl, float* __restrict__ mem, bf16* __restrict__ spkb,
                float* __restrict__ outp)
{
    const int tid = threadIdx.x, lane = tid & 63, w = tid >> 6;
    const int m0 = blockIdx.y * 16;
    const int q = lane >> 4, kq = q * 8;
    const bf16* ap  = Ab  + (size_t)(m0 + (lane & 15)) * N2_ + w * 256 + kq;
    const bf16* bhp = WTh + (size_t)(blockIdx.x * 16 + (lane & 15)) * N2_ + w * 256 + kq;
    const bf16* blp = WTl + (size_t)(blockIdx.x * 16 + (lane & 15)) * N2_ + w * 256 + kq;
    f32x4 acc = {0, 0, 0, 0};
#pragma unroll 4
    for (int s = 0; s < 8; ++s) {
        bf16x8 a = *(const bf16x8*)(ap + s * 32);
        acc = MFMA16(a, *(const bf16x8*)(bhp + s * 32), acc);
        acc = MFMA16(a, *(const bf16x8*)(blp + s * 32), acc);
    }
    __shared__ f32x4 red[3][64];
    if (w) red[w - 1][lane] = acc;
    __syncthreads();
    if (w == 0) {
#pragma unroll
        for (int j = 0; j < 3; ++j) {
            f32x4 o = red[j][lane];
            acc.x += o.x; acc.y += o.y; acc.z += o.z; acc.w += o.w;
        }
#pragma unroll
        for (int r = 0; r < 4; ++r) {
            size_t idx = (size_t)(m0 + q * 4 + r) * N3_ + blockIdx.x * 16 + (lane & 15);
            float m = mem[idx] * 0.5f * (1.0f - (float)spkb[idx]) + acc[r];
            mem[idx] = m;
            spkb[idx] = (m > 0.3f) ? (bf16)1.0f : (bf16)0.0f;
            if (outp) outp[idx] = (m > 0.3f) ? 1.0f : 0.0f;
        }
    }
}

__global__ __launch_bounds__(256)
void stage_l0_raw(const float* __restrict__ x, int t,
                  const bf16* __restrict__ WTh, const bf16* __restrict__ WTl,
                  float* __restrict__ mem0, bf16* __restrict__ spk0b)
{
    const int tid = threadIdx.x, lane = tid & 63, w = tid >> 6;
    const int mh = w & 1, kh = w >> 1;
    const int m0 = blockIdx.y * 32 + mh * 16;
    const int q = lane >> 4, kq = q * 8;
    const int row = m0 + (lane & 15);
    const bf16* bhp = WTh + (size_t)(blockIdx.x * 16 + (lane & 15)) * D0_ + kh * 256 + kq;
    const bf16* blp = WTl + (size_t)(blockIdx.x * 16 + (lane & 15)) * D0_ + kh * 256 + kq;
    const float* xp = x + ((size_t)row * D0_ + kh * 256 + kq) * T_ + t;
    f32x4 acc = {0, 0, 0, 0};
#pragma unroll 2
    for (int s = 0; s < 8; ++s) {
        bf16x8 ah, al;
#pragma unroll
        for (int j = 0; j < 8; ++j) {
            float v = xp[(size_t)(s * 32 + j) * T_];
            bf16 h = (bf16)v;
            ah[j] = h;
            al[j] = (bf16)(v - (float)h);
        }
        bf16x8 bh = *(const bf16x8*)(bhp + s * 32);
        bf16x8 bl = *(const bf16x8*)(blp + s * 32);
        acc = MFMA16(ah, bh, acc);
        acc = MFMA16(al, bh, acc);
        acc = MFMA16(ah, bl, acc);
    }
    __shared__ f32x4 red[2][64];
    if (kh == 1) red[mh][lane] = acc;
    __syncthreads();
    if (kh == 0) {
        f32x4 o = red[mh][lane];
        acc.x += o.x; acc.y += o.y; acc.z += o.z; acc.w += o.w;
#pragma unroll
        for (int r = 0; r < 4; ++r) {
            size_t idx = (size_t)(m0 + q * 4 + r) * N1_ + blockIdx.x * 16 + (lane & 15);
            float m = mem0[idx] * 0.5f * (1.0f - (float)spk0b[idx]) + acc[r];
            mem0[idx] = m;
            spk0b[idx] = (m > 0.3f) ? (bf16)1.0f : (bf16)0.0f;
        }
    }
}

extern "C" void kernel_launch(void* const* d_in, const int* in_sizes, int n_in,
                              void* d_out, int out_size, void* d_ws, size_t ws_size,
                              hipStream_t stream)
{
    const float* x  = (const float*)d_in[0];
    const float* w0 = (const float*)d_in[1];
    const float* w1 = (const float*)d_in[2];
    const float* w2 = (const float*)d_in[3];
    float* out = (float*)d_out;

    char* p = (char*)d_ws;
    bf16* w0h = (bf16*)p;  p += (size_t)N1_ * D0_ * 2;
    bf16* w0l = (bf16*)p;  p += (size_t)N1_ * D0_ * 2;
    bf16* w1h = (bf16*)p;  p += (size_t)N2_ * N1_ * 2;
    bf16* w1l = (bf16*)p;  p += (size_t)N2_ * N1_ * 2;
    bf16* w2h = (bf16*)p;  p += (size_t)N3_ * N2_ * 2;
    bf16* w2l = (bf16*)p;  p += (size_t)N3_ * N2_ * 2;
    // fallback states
    char* statep = p;
    float* mem0 = (float*)p;  p += (size_t)B_ * N1_ * 4;
    bf16*  spk0b = (bf16*)p;  p += (size_t)B_ * N1_ * 2;
    float* mem1 = (float*)p;  p += (size_t)B_ * N2_ * 4;
    bf16*  spk1b = (bf16*)p;  p += (size_t)B_ * N2_ * 2;
    float* mem2 = (float*)p;  p += (size_t)B_ * N3_ * 4;
    bf16*  spk2b = (bf16*)p;  p += (size_t)B_ * N3_ * 2;
    size_t stateBytes = (size_t)(p - statep);
    // big aliased regions (tier 1)
    char* regA = p;  p += (size_t)TB_ * N1_ * 2;   // max(Xh, spk0, I2) = 134 MB
    char* regB = p;  p += (size_t)TB_ * N2_ * 2;   // max(Xl, spk1)     = 134 MB
    char* regQ = p;  p += (size_t)TB_ * N1_ * 4;   // max(I0, I1)       = 268 MB
    size_t needBytes = (size_t)(p - (char*)d_ws);

    const bool tier1 = (ws_size >= needBytes);

    split_w<<<dim3(D0_/32, N1_/32), 256, 0, stream>>>(w0, w0h, w0l, D0_, N1_);
    split_w<<<dim3(N1_/32, N2_/32), 256, 0, stream>>>(w1, w1h, w1l, N1_, N2_);
    split_w<<<dim3(N2_/32, N3_/32), 256, 0, stream>>>(w2, w2h, w2l, N2_, N3_);

    if (tier1) {
        bf16*  Xh   = (bf16*)regA;
        bf16*  Xl   = (bf16*)regB;
        float* I0   = (float*)regQ;
        // 1) transpose + hi/lo split of inputs
        split_x<<<dim3(D0_/32, T_/32, B_), 256, 0, stream>>>(x, Xh, Xl);
        // 2) I0 = X @ w0  (3-term split), M=65536 K=512 N=1024
        gemm128<D0_, true><<<dim3(N1_/128, TB_/128), 256, 0, stream>>>(
            Xh, Xl, w0h, w0l, I0, N1_);
        // 3) L0 temporal scan -> spk0 train (regA; Xh dead)
        bf16* spk0 = (bf16*)regA;
        scan_train<<<(B_*N1_)/256, 256, 0, stream>>>(I0, spk0, B_ * N1_);
        // 4) I1 = spk0 @ w1, M=65536 K=1024 N=1024 (regQ; I0 dead)
        float* I1 = (float*)regQ;
        gemm128<N1_, false><<<dim3(N2_/128, TB_/128), 256, 0, stream>>>(
            spk0, nullptr, w1h, w1l, I1, N2_);
        // 5) L1 scan -> spk1 train (regB; Xl dead)
        bf16* spk1 = (bf16*)regB;
        scan_train<<<(B_*N2_)/256, 256, 0, stream>>>(I1, spk1, B_ * N2_);
        // 6) I2 = spk1 @ w2, M=65536 K=1024 N=512 (regA; spk0 dead)
        float* I2 = (float*)regA;
        gemm128<N2_, false><<<dim3(N3_/128, TB_/128), 256, 0, stream>>>(
            spk1, nullptr, w2h, w2l, I2, N3_);
        // 7) L2 scan -> final spikes to d_out
        scan_out<<<(B_*N3_)/256, 256, 0, stream>>>(I2, out, B_ * N3_);
    } else {
        hipMemsetAsync(statep, 0, stateBytes, stream);
        for (int t = 0; t < T_; ++t) {
            stage_l0_raw<<<dim3(N1_/16, B_/32), 256, 0, stream>>>(x, t, w0h, w0l, mem0, spk0b);
            stage_mid<<<dim3(N2_/16, B_/32), 256, 0, stream>>>(spk0b, w1h, w1l, mem1, spk1b);
            stage_last<<<dim3(N3_/16, B_/16), 256, 0, stream>>>(
                spk1b, w2h, w2l, mem2, spk2b, (t == T_-1) ? out : nullptr);
        }
        (void)mem2; (void)spk2b;
    }
}

// Round 4
// 1897.746 us; speedup vs baseline: 10.0473x; 10.0473x over previous
//
#include <hip/hip_runtime.h>

// SNN B=128, D0=512, T=512, dims 1024/1024/512, DECAY=0.5, THRESH=0.3
// Round 4: time-chunked 3-GEMM + 3-scan pipeline. Chunk size Tc chosen at
// runtime to fit ws_size (evidence: ws in [413 MB, 547 MB) -> Tc=256, 2 chunks).
// Per chunk: split_x -> gemm I0 -> scan L0 -> gemm I1 -> scan L1 -> gemm I2 -> scan L2.
// Buffers: bufX (Xh|Xl, reused as spk1), bufS0 (spk0), bufI (I0->I1->I2).

typedef __bf16 bf16;
typedef __attribute__((ext_vector_type(8))) __bf16 bf16x8;
typedef __attribute__((ext_vector_type(4))) float f32x4;

#define B_   128
#define D0_  512
#define T_   512
#define N1_  1024
#define N2_  1024
#define N3_  512
#define MFMA16(a,b,c) __builtin_amdgcn_mfma_f32_16x16x32_bf16((a),(b),(c),0,0,0)

// ---------- setup ----------

// W [K][N] fp32 -> WTh/WTl [N][K] bf16 (transposed hi/lo split)
__global__ __launch_bounds__(256)
void split_w(const float* __restrict__ W, bf16* __restrict__ WTh, bf16* __restrict__ WTl,
             int K, int N)
{
    __shared__ float tile[32][33];
    const int k0 = blockIdx.x * 32, n0 = blockIdx.y * 32;
    const int tx = threadIdx.x & 31, ty = threadIdx.x >> 5;
#pragma unroll
    for (int r = 0; r < 4; ++r)
        tile[ty + r * 8][tx] = W[(size_t)(k0 + ty + r * 8) * N + n0 + tx];
    __syncthreads();
#pragma unroll
    for (int r = 0; r < 4; ++r) {
        int nl = ty + r * 8;
        float v = tile[tx][nl];
        bf16 h = (bf16)v;
        size_t o = (size_t)(n0 + nl) * K + k0 + tx;
        WTh[o] = h;
        WTl[o] = (bf16)(v - (float)h);
    }
}

// x [B][D0][T] fp32, chunk [t0, t0+Tc) -> Xh/Xl [Tc*B][D0] bf16 (hi/lo, time-major)
// grid (D0/32, Tc/32, B)
__global__ __launch_bounds__(256)
void split_x_chunk(const float* __restrict__ in, bf16* __restrict__ Xh,
                   bf16* __restrict__ Xl, int t0)
{
    __shared__ float tile[32][33];
    const int b = blockIdx.z, d0 = blockIdx.x * 32, lt0 = blockIdx.y * 32;
    const int tx = threadIdx.x & 31, ty = threadIdx.x >> 5;
#pragma unroll
    for (int r = 0; r < 4; ++r) {
        int d = ty + r * 8;
        tile[d][tx] = in[((size_t)b * D0_ + d0 + d) * T_ + t0 + lt0 + tx];
    }
    __syncthreads();
#pragma unroll
    for (int r = 0; r < 4; ++r) {
        int lt = lt0 + ty + r * 8;
        float v = tile[tx][ty + r * 8];
        bf16 h = (bf16)v;
        size_t o = ((size_t)lt * B_ + b) * D0_ + d0 + tx;
        Xh[o] = h;
        Xl[o] = (bf16)(v - (float)h);
    }
}

// ---------- GEMM: C[M][N] = A[M][K] @ WT[N][K]^T ----------
// 256 thr = 4 waves (2x2), block tile 128x128, wave 64x64 (4x4 MFMA frags).
// Direct global loads (B is L2-hot, A streams via L3). Register-safe:
// B frags loaded per-ni, s-loop not unrolled, VGPR capped via launch_bounds.
template<int K, bool SPLITA>
__global__ __launch_bounds__(256, 2)
void gemm128(const bf16* __restrict__ Ah, const bf16* __restrict__ Al,
             const bf16* __restrict__ WTh, const bf16* __restrict__ WTl,
             float* __restrict__ C, int N)
{
    const int tid = threadIdx.x, lane = tid & 63, w = tid >> 6;
    const int wm = w & 1, wn = w >> 1;
    const int r15 = lane & 15, q = lane >> 4, kq = q * 8;
    const size_t mb = (size_t)blockIdx.y * 128 + wm * 64;
    const int nb = blockIdx.x * 128 + wn * 64;

    const bf16* ap  = Ah + (mb + r15) * K + kq;
    const bf16* alp = SPLITA ? (Al + (mb + r15) * K + kq) : nullptr;
    const bf16* bhp = WTh + (size_t)(nb + r15) * K + kq;
    const bf16* blp = WTl + (size_t)(nb + r15) * K + kq;

    f32x4 acc[4][4] = {};
#pragma unroll 1
    for (int s = 0; s < K / 32; ++s) {
        const int o = s * 32;
        bf16x8 a[4], al2[4];
#pragma unroll
        for (int mi = 0; mi < 4; ++mi) {
            a[mi] = *(const bf16x8*)(ap + (size_t)mi * 16 * K + o);
            if constexpr (SPLITA)
                al2[mi] = *(const bf16x8*)(alp + (size_t)mi * 16 * K + o);
        }
#pragma unroll
        for (int ni = 0; ni < 4; ++ni) {
            bf16x8 bh = *(const bf16x8*)(bhp + (size_t)ni * 16 * K + o);
            bf16x8 bl = *(const bf16x8*)(blp + (size_t)ni * 16 * K + o);
#pragma unroll
            for (int mi = 0; mi < 4; ++mi) {
                acc[mi][ni] = MFMA16(a[mi], bh, acc[mi][ni]);
                if constexpr (SPLITA)
                    acc[mi][ni] = MFMA16(al2[mi], bh, acc[mi][ni]);
                acc[mi][ni] = MFMA16(a[mi], bl, acc[mi][ni]);
            }
        }
    }
#pragma unroll
    for (int mi = 0; mi < 4; ++mi)
#pragma unroll
        for (int ni = 0; ni < 4; ++ni)
#pragma unroll
            for (int r = 0; r < 4; ++r)
                C[(mb + mi * 16 + q * 4 + r) * N + nb + ni * 16 + r15] = acc[mi][ni][r];
}

// ---------- temporal scans (parallel over B*N neurons, sequential over Tc) ----------

// I [Tc][BN] f32 -> S [Tc][BN] bf16 spikes; carries mem/spk state across chunks
__global__ __launch_bounds__(256)
void scan_chunk(const float* __restrict__ I, bf16* __restrict__ S,
                float* __restrict__ mem_st, bf16* __restrict__ spk_st,
                int BN, int Tc)
{
    const int i = blockIdx.x * 256 + threadIdx.x;
    float m = mem_st[i];
    float s = (float)spk_st[i];
#pragma unroll 8
    for (int t = 0; t < Tc; ++t) {
        float v = I[(size_t)t * BN + i];
        m = m * 0.5f * (1.0f - s) + v;
        s = (m > 0.3f) ? 1.0f : 0.0f;
        S[(size_t)t * BN + i] = (bf16)s;
    }
    mem_st[i] = m;
    spk_st[i] = (bf16)s;
}

// Final layer: no spike train needed; write d_out on the last chunk only.
__global__ __launch_bounds__(256)
void scan_chunk_out(const float* __restrict__ I, float* __restrict__ mem_st,
                    bf16* __restrict__ spk_st, float* __restrict__ outp,
                    int BN, int Tc)
{
    const int i = blockIdx.x * 256 + threadIdx.x;
    float m = mem_st[i];
    float s = (float)spk_st[i];
#pragma unroll 8
    for (int t = 0; t < Tc; ++t) {
        float v = I[(size_t)t * BN + i];
        m = m * 0.5f * (1.0f - s) + v;
        s = (m > 0.3f) ? 1.0f : 0.0f;
    }
    mem_st[i] = m;
    spk_st[i] = (bf16)s;
    if (outp) outp[i] = s;
}

extern "C" void kernel_launch(void* const* d_in, const int* in_sizes, int n_in,
                              void* d_out, int out_size, void* d_ws, size_t ws_size,
                              hipStream_t stream)
{
    const float* x  = (const float*)d_in[0];
    const float* w0 = (const float*)d_in[1];
    const float* w1 = (const float*)d_in[2];
    const float* w2 = (const float*)d_in[3];
    float* out = (float*)d_out;

    char* p = (char*)d_ws;
    // scan states (contiguous -> one memset)
    float* mem0  = (float*)p;  p += (size_t)B_ * N1_ * 4;
    bf16*  spst0 = (bf16*)p;   p += (size_t)B_ * N1_ * 2;
    float* mem1  = (float*)p;  p += (size_t)B_ * N2_ * 4;
    bf16*  spst1 = (bf16*)p;   p += (size_t)B_ * N2_ * 2;
    float* mem2  = (float*)p;  p += (size_t)B_ * N3_ * 4;
    bf16*  spst2 = (bf16*)p;   p += (size_t)B_ * N3_ * 2;
    size_t stateBytes = (size_t)(p - (char*)d_ws);
    // weight splits (written fully by split_w, no init needed)
    bf16* w0h = (bf16*)p;  p += (size_t)N1_ * D0_ * 2;
    bf16* w0l = (bf16*)p;  p += (size_t)N1_ * D0_ * 2;
    bf16* w1h = (bf16*)p;  p += (size_t)N2_ * N1_ * 2;
    bf16* w1l = (bf16*)p;  p += (size_t)N2_ * N1_ * 2;
    bf16* w2h = (bf16*)p;  p += (size_t)N3_ * N2_ * 2;
    bf16* w2l = (bf16*)p;  p += (size_t)N3_ * N2_ * 2;
    size_t fixedBytes = (size_t)(p - (char*)d_ws);

    // pick chunk count: per-chunk buffers cost Tc * 1 MiB
    //   bufX  = Tc*B*D0*2*2 = Tc*256KiB  (Xh|Xl; reused as spk1, same size)
    //   bufS0 = Tc*B*N1*2   = Tc*256KiB
    //   bufI  = Tc*B*1024*4 = Tc*512KiB  (I0 -> I1 -> I2)
    int nc = 1;
    while (nc < 16 && fixedBytes + (size_t)(T_ / nc) * 1048576ull > ws_size) nc *= 2;
    const int Tc = T_ / nc;

    char* bufX  = p;
    char* bufS0 = bufX + (size_t)Tc * 262144;
    char* bufI  = bufS0 + (size_t)Tc * 262144;

    bf16*  Xh   = (bf16*)bufX;
    bf16*  Xl   = (bf16*)(bufX + (size_t)Tc * 131072);
    bf16*  spk0 = (bf16*)bufS0;
    bf16*  spk1 = (bf16*)bufX;         // Xh/Xl dead after gemm I0
    float* I    = (float*)bufI;

    hipMemsetAsync(d_ws, 0, stateBytes, stream);
    split_w<<<dim3(D0_/32, N1_/32), 256, 0, stream>>>(w0, w0h, w0l, D0_, N1_);
    split_w<<<dim3(N1_/32, N2_/32), 256, 0, stream>>>(w1, w1h, w1l, N1_, N2_);
    split_w<<<dim3(N2_/32, N3_/32), 256, 0, stream>>>(w2, w2h, w2l, N2_, N3_);

    for (int c = 0; c < nc; ++c) {
        const int t0 = c * Tc;
        // 1) transpose + hi/lo split of this time chunk
        split_x_chunk<<<dim3(D0_/32, Tc/32, B_), 256, 0, stream>>>(x, Xh, Xl, t0);
        // 2) I0 = X @ w0   [Tc*128 x 512] x [512 x 1024], 3-term split
        gemm128<D0_, true><<<dim3(N1_/128, Tc), 256, 0, stream>>>(
            Xh, Xl, w0h, w0l, I, N1_);
        // 3) L0 scan -> spk0 train
        scan_chunk<<<(B_*N1_)/256, 256, 0, stream>>>(I, spk0, mem0, spst0, B_*N1_, Tc);
        // 4) I1 = spk0 @ w1  [Tc*128 x 1024] x [1024 x 1024], 2-term (A exact)
        gemm128<N1_, false><<<dim3(N2_/128, Tc), 256, 0, stream>>>(
            spk0, nullptr, w1h, w1l, I, N2_);
        // 5) L1 scan -> spk1 train (overwrites Xh/Xl)
        scan_chunk<<<(B_*N2_)/256, 256, 0, stream>>>(I, spk1, mem1, spst1, B_*N2_, Tc);
        // 6) I2 = spk1 @ w2  [Tc*128 x 1024] x [1024 x 512]
        gemm128<N2_, false><<<dim3(N3_/128, Tc), 256, 0, stream>>>(
            spk1, nullptr, w2h, w2l, I, N3_);
        // 7) L2 scan; final chunk writes d_out
        scan_chunk_out<<<(B_*N3_)/256, 256, 0, stream>>>(
            I, mem2, spst2, (c == nc - 1) ? out : nullptr, B_*N3_, Tc);
    }
}

// Round 5
// 1128.516 us; speedup vs baseline: 16.8958x; 1.6816x over previous
//
#include <hip/hip_runtime.h>

// SNN B=128, D0=512, T=512, dims 1024/1024/512, DECAY=0.5, THRESH=0.3
// Round 5: time-chunked 3-GEMM + 3-scan pipeline (round 4) with the GEMM
// rebuilt in the m97 style: 128x128 tile, BK=32, LDS staging via
// global_load_lds width=16, ds_read_b128 fragments, 2-barrier K-loop.

typedef __bf16 bf16;
typedef __attribute__((ext_vector_type(8))) __bf16 bf16x8;
typedef __attribute__((ext_vector_type(4))) float f32x4;

#define B_   128
#define D0_  512
#define T_   512
#define N1_  1024
#define N2_  1024
#define N3_  512
#define MFMA16(a,b,c) __builtin_amdgcn_mfma_f32_16x16x32_bf16((a),(b),(c),0,0,0)

// async global->LDS, 16B per lane; LDS dest = wave-uniform base + lane*16
#define GL2LDS(g, l) __builtin_amdgcn_global_load_lds( \
    (const __attribute__((address_space(1))) void*)(g), \
    (__attribute__((address_space(3))) void*)(l), 16, 0, 0)

// ---------- setup ----------

// W [K][N] fp32 -> WTh/WTl [N][K] bf16 (transposed hi/lo split)
__global__ __launch_bounds__(256)
void split_w(const float* __restrict__ W, bf16* __restrict__ WTh, bf16* __restrict__ WTl,
             int K, int N)
{
    __shared__ float tile[32][33];
    const int k0 = blockIdx.x * 32, n0 = blockIdx.y * 32;
    const int tx = threadIdx.x & 31, ty = threadIdx.x >> 5;
#pragma unroll
    for (int r = 0; r < 4; ++r)
        tile[ty + r * 8][tx] = W[(size_t)(k0 + ty + r * 8) * N + n0 + tx];
    __syncthreads();
#pragma unroll
    for (int r = 0; r < 4; ++r) {
        int nl = ty + r * 8;
        float v = tile[tx][nl];
        bf16 h = (bf16)v;
        size_t o = (size_t)(n0 + nl) * K + k0 + tx;
        WTh[o] = h;
        WTl[o] = (bf16)(v - (float)h);
    }
}

// x [B][D0][T] fp32, chunk [t0, t0+Tc) -> Xh/Xl [Tc*B][D0] bf16 (hi/lo, time-major)
__global__ __launch_bounds__(256)
void split_x_chunk(const float* __restrict__ in, bf16* __restrict__ Xh,
                   bf16* __restrict__ Xl, int t0)
{
    __shared__ float tile[32][33];
    const int b = blockIdx.z, d0 = blockIdx.x * 32, lt0 = blockIdx.y * 32;
    const int tx = threadIdx.x & 31, ty = threadIdx.x >> 5;
#pragma unroll
    for (int r = 0; r < 4; ++r) {
        int d = ty + r * 8;
        tile[d][tx] = in[((size_t)b * D0_ + d0 + d) * T_ + t0 + lt0 + tx];
    }
    __syncthreads();
#pragma unroll
    for (int r = 0; r < 4; ++r) {
        int lt = lt0 + ty + r * 8;
        float v = tile[tx][ty + r * 8];
        bf16 h = (bf16)v;
        size_t o = ((size_t)lt * B_ + b) * D0_ + d0 + tx;
        Xh[o] = h;
        Xl[o] = (bf16)(v - (float)h);
    }
}

// ---------- GEMM: C[M][N] = A[M][K] @ WT[N][K]^T  (m97-style LDS staging) ----------
// 256 thr = 4 waves (2x2), block tile 128x128, wave 64x64 (4x4 MFMA frags).
// LDS tiles [128 rows][32 k] bf16, 64 B/row; staged via global_load_lds x16.
// grid (M/128, N/128): M-tiles fastest so A-chunk stays L3-resident across N revisits.
template<int K, bool SPLITA>
__global__ __launch_bounds__(256)
void gemm_lds(const bf16* __restrict__ Ah, const bf16* __restrict__ Al,
              const bf16* __restrict__ WTh, const bf16* __restrict__ WTl,
              float* __restrict__ C, int N)
{
    __shared__ bf16 sAh[128 * 32];
    __shared__ bf16 sAl[128 * 32];
    __shared__ bf16 sBh[128 * 32];
    __shared__ bf16 sBl[128 * 32];

    const int tid = threadIdx.x, lane = tid & 63, w = tid >> 6;
    const int wm = w & 1, wn = w >> 1;
    const int r15 = lane & 15, q = lane >> 4;
    const size_t mb = (size_t)blockIdx.x * 128;
    const int nb = blockIdx.y * 128;

    // staging: wave w covers tile rows [w*32, w*32+32), 2 insts of 16 rows each;
    // lane -> (row = lane>>2, 16B chunk = lane&3) within a 16-row slab.
    const int i4 = lane >> 2, c4 = lane & 3;
    const bf16* gA  = Ah  + (mb + w * 32 + i4) * K + c4 * 8;
    const bf16* gAl = SPLITA ? (Al + (mb + w * 32 + i4) * K + c4 * 8) : nullptr;
    const bf16* gBh = WTh + (size_t)(nb + w * 32 + i4) * K + c4 * 8;
    const bf16* gBl = WTl + (size_t)(nb + w * 32 + i4) * K + c4 * 8;
    bf16* lA  = sAh + w * 32 * 32;
    bf16* lAl = sAl + w * 32 * 32;
    bf16* lBh = sBh + w * 32 * 32;
    bf16* lBl = sBl + w * 32 * 32;

    f32x4 acc[4][4] = {};

#pragma unroll 1
    for (int s = 0; s < K / 32; ++s) {
        const int go = s * 32;                     // element offset along K
        __syncthreads();                           // prev tile consumed
#pragma unroll
        for (int inst = 0; inst < 2; ++inst) {
            GL2LDS(gA + (size_t)inst * 16 * K + go, lA + inst * 16 * 32);
            if constexpr (SPLITA)
                GL2LDS(gAl + (size_t)inst * 16 * K + go, lAl + inst * 16 * 32);
            GL2LDS(gBh + (size_t)inst * 16 * K + go, lBh + inst * 16 * 32);
            GL2LDS(gBl + (size_t)inst * 16 * K + go, lBl + inst * 16 * 32);
        }
        __syncthreads();                           // staging drained (vmcnt(0))

        bf16x8 a[4], al2[4];
#pragma unroll
        for (int mi = 0; mi < 4; ++mi) {
            a[mi] = *(const bf16x8*)(sAh + (wm * 64 + mi * 16 + r15) * 32 + q * 8);
            if constexpr (SPLITA)
                al2[mi] = *(const bf16x8*)(sAl + (wm * 64 + mi * 16 + r15) * 32 + q * 8);
        }
#pragma unroll
        for (int ni = 0; ni < 4; ++ni) {
            bf16x8 bh = *(const bf16x8*)(sBh + (wn * 64 + ni * 16 + r15) * 32 + q * 8);
            bf16x8 bl = *(const bf16x8*)(sBl + (wn * 64 + ni * 16 + r15) * 32 + q * 8);
#pragma unroll
            for (int mi = 0; mi < 4; ++mi) {
                acc[mi][ni] = MFMA16(a[mi], bh, acc[mi][ni]);
                if constexpr (SPLITA)
                    acc[mi][ni] = MFMA16(al2[mi], bh, acc[mi][ni]);
                acc[mi][ni] = MFMA16(a[mi], bl, acc[mi][ni]);
            }
        }
    }
#pragma unroll
    for (int mi = 0; mi < 4; ++mi)
#pragma unroll
        for (int ni = 0; ni < 4; ++ni)
#pragma unroll
            for (int r = 0; r < 4; ++r)
                C[(mb + wm * 64 + mi * 16 + q * 4 + r) * N + nb + wn * 64 + ni * 16 + r15]
                    = acc[mi][ni][r];
}

// ---------- temporal scans ----------

__global__ __launch_bounds__(256)
void scan_chunk(const float* __restrict__ I, bf16* __restrict__ S,
                float* __restrict__ mem_st, bf16* __restrict__ spk_st,
                int BN, int Tc)
{
    const int i = blockIdx.x * 256 + threadIdx.x;
    float m = mem_st[i];
    float s = (float)spk_st[i];
#pragma unroll 8
    for (int t = 0; t < Tc; ++t) {
        float v = I[(size_t)t * BN + i];
        m = m * 0.5f * (1.0f - s) + v;
        s = (m > 0.3f) ? 1.0f : 0.0f;
        S[(size_t)t * BN + i] = (bf16)s;
    }
    mem_st[i] = m;
    spk_st[i] = (bf16)s;
}

__global__ __launch_bounds__(256)
void scan_chunk_out(const float* __restrict__ I, float* __restrict__ mem_st,
                    bf16* __restrict__ spk_st, float* __restrict__ outp,
                    int BN, int Tc)
{
    const int i = blockIdx.x * 256 + threadIdx.x;
    float m = mem_st[i];
    float s = (float)spk_st[i];
#pragma unroll 8
    for (int t = 0; t < Tc; ++t) {
        float v = I[(size_t)t * BN + i];
        m = m * 0.5f * (1.0f - s) + v;
        s = (m > 0.3f) ? 1.0f : 0.0f;
    }
    mem_st[i] = m;
    spk_st[i] = (bf16)s;
    if (outp) outp[i] = s;
}

extern "C" void kernel_launch(void* const* d_in, const int* in_sizes, int n_in,
                              void* d_out, int out_size, void* d_ws, size_t ws_size,
                              hipStream_t stream)
{
    const float* x  = (const float*)d_in[0];
    const float* w0 = (const float*)d_in[1];
    const float* w1 = (const float*)d_in[2];
    const float* w2 = (const float*)d_in[3];
    float* out = (float*)d_out;

    char* p = (char*)d_ws;
    float* mem0  = (float*)p;  p += (size_t)B_ * N1_ * 4;
    bf16*  spst0 = (bf16*)p;   p += (size_t)B_ * N1_ * 2;
    float* mem1  = (float*)p;  p += (size_t)B_ * N2_ * 4;
    bf16*  spst1 = (bf16*)p;   p += (size_t)B_ * N2_ * 2;
    float* mem2  = (float*)p;  p += (size_t)B_ * N3_ * 4;
    bf16*  spst2 = (bf16*)p;   p += (size_t)B_ * N3_ * 2;
    size_t stateBytes = (size_t)(p - (char*)d_ws);
    bf16* w0h = (bf16*)p;  p += (size_t)N1_ * D0_ * 2;
    bf16* w0l = (bf16*)p;  p += (size_t)N1_ * D0_ * 2;
    bf16* w1h = (bf16*)p;  p += (size_t)N2_ * N1_ * 2;
    bf16* w1l = (bf16*)p;  p += (size_t)N2_ * N1_ * 2;
    bf16* w2h = (bf16*)p;  p += (size_t)N3_ * N2_ * 2;
    bf16* w2l = (bf16*)p;  p += (size_t)N3_ * N2_ * 2;
    size_t fixedBytes = (size_t)(p - (char*)d_ws);

    // per-chunk buffers cost Tc * 1 MiB total
    int nc = 1;
    while (nc < 16 && fixedBytes + (size_t)(T_ / nc) * 1048576ull > ws_size) nc *= 2;
    const int Tc = T_ / nc;

    char* bufX  = p;
    char* bufS0 = bufX + (size_t)Tc * 262144;
    char* bufI  = bufS0 + (size_t)Tc * 262144;

    bf16*  Xh   = (bf16*)bufX;
    bf16*  Xl   = (bf16*)(bufX + (size_t)Tc * 131072);
    bf16*  spk0 = (bf16*)bufS0;
    bf16*  spk1 = (bf16*)bufX;          // Xh/Xl dead after gemm I0
    float* I    = (float*)bufI;

    hipMemsetAsync(d_ws, 0, stateBytes, stream);
    split_w<<<dim3(D0_/32, N1_/32), 256, 0, stream>>>(w0, w0h, w0l, D0_, N1_);
    split_w<<<dim3(N1_/32, N2_/32), 256, 0, stream>>>(w1, w1h, w1l, N1_, N2_);
    split_w<<<dim3(N2_/32, N3_/32), 256, 0, stream>>>(w2, w2h, w2l, N2_, N3_);

    for (int c = 0; c < nc; ++c) {
        const int t0 = c * Tc;
        // 1) transpose + hi/lo split of this time chunk
        split_x_chunk<<<dim3(D0_/32, Tc/32, B_), 256, 0, stream>>>(x, Xh, Xl, t0);
        // 2) I0 = X @ w0   [Tc*128 x 512] x [512 x 1024], 3-term split
        gemm_lds<D0_, true><<<dim3(Tc, N1_/128), 256, 0, stream>>>(
            Xh, Xl, w0h, w0l, I, N1_);
        // 3) L0 scan -> spk0 train
        scan_chunk<<<(B_*N1_)/256, 256, 0, stream>>>(I, spk0, mem0, spst0, B_*N1_, Tc);
        // 4) I1 = spk0 @ w1  [Tc*128 x 1024] x [1024 x 1024], 2-term (A exact)
        gemm_lds<N1_, false><<<dim3(Tc, N2_/128), 256, 0, stream>>>(
            spk0, nullptr, w1h, w1l, I, N2_);
        // 5) L1 scan -> spk1 train (overwrites Xh/Xl)
        scan_chunk<<<(B_*N2_)/256, 256, 0, stream>>>(I, spk1, mem1, spst1, B_*N2_, Tc);
        // 6) I2 = spk1 @ w2  [Tc*128 x 1024] x [1024 x 512]
        gemm_lds<N2_, false><<<dim3(Tc, N3_/128), 256, 0, stream>>>(
            spk1, nullptr, w2h, w2l, I, N3_);
        // 7) L2 scan; final chunk writes d_out
        scan_chunk_out<<<(B_*N3_)/256, 256, 0, stream>>>(
            I, mem2, spst2, (c == nc - 1) ? out : nullptr, B_*N3_, Tc);
    }
}